// Round 12
// baseline (64.334 us; speedup 1.0000x reference)
//
#include <hip/hip_runtime.h>
#include <math.h>

#define NQ 4
#define NL 6
#define BATCH 524288
#define EPT 8
#define LP 17   // padded row stride (float2) for V-build matmuls
#define NBLK (BATCH / (256 * EPT))   // 256 blocks -> 1 per CU, all co-resident

struct C2 { float re, im; };

__device__ __forceinline__ C2 cmul(C2 a, C2 b) {
    return C2{ __builtin_fmaf(a.re, b.re, -a.im * b.im),
               __builtin_fmaf(a.re, b.im,  a.im * b.re) };
}

// ---------------------------------------------------------------------------
// ONE kernel (single graph node: every 2-node graph pays ~20us barrier).
// R9 structure with V-build amortized 4x: 256 blocks (1/CU) x EPT=8.
//   0) all threads: 8 coalesced x loads + sincos + m[8][16] (regs; ~220 VGPR,
//      launch_bounds(256,1) so no spill at 1 wave/SIMD by design)
//   1) tid<24: fused U = RZ*RY*RX gates -> sU                    [barrier]
//   2) layer matrices L_l[r][c] = prod_q U_q[r_q][perm(c)_q]     [barrier]
//   3) tree matmul A=L1*L0,B=L3*L2,C=L5*L4 / D=B*A / V=C*D,
//      fold (-i)^popcount(c) -> sV4                              [barriers]
//   4) matvec: per row 8 broadcast b128 reads amortized over 8 elements
//      (256 fma : 8 LDS), ev_q = sum_r z_q(r)|psi_r|^2, coalesced store.
// ---------------------------------------------------------------------------
__global__ __launch_bounds__(256, 1) void qone8_kernel(const float4* __restrict__ x,
                                                       const float* __restrict__ w,
                                                       float4* __restrict__ out) {
    __shared__ float  sU[NL * NQ * 8];
    __shared__ float2 sL[NL][16 * LP];
    __shared__ float2 sP[3][16 * LP];
    __shared__ float2 sDm[16 * LP];
    __shared__ float4 sV4[128];              // V rows for matvec

    const int tid = threadIdx.x;
    const int base = blockIdx.x * (256 * EPT) + tid;

    // ---- 0) per-element Kronecker vectors (8 elements, regs) ----
    float m[EPT][16];
#pragma unroll
    for (int e = 0; e < EPT; ++e) {
        const float4 xv = x[base + e * 256];
        float c0, s0, c1, s1, c2, s2, c3, s3;
        __sincosf(0.5f * xv.x, &s0, &c0);
        __sincosf(0.5f * xv.y, &s1, &c1);
        __sincosf(0.5f * xv.z, &s2, &c2);
        __sincosf(0.5f * xv.w, &s3, &c3);
        float ab[4];
        ab[0] = c0 * c1; ab[1] = c0 * s1; ab[2] = s0 * c1; ab[3] = s0 * s1;
        float abc[8];
#pragma unroll
        for (int k = 0; k < 4; ++k) { abc[2 * k] = ab[k] * c2; abc[2 * k + 1] = ab[k] * s2; }
#pragma unroll
        for (int k = 0; k < 8; ++k) { m[e][2 * k] = abc[k] * c3; m[e][2 * k + 1] = abc[k] * s3; }
    }

    // ---- 1) fused gate matrices (24 threads) ----
    if (tid < NL * NQ) {
        const float a = w[tid * 3 + 0];
        const float b = w[tid * 3 + 1];
        const float g = w[tid * 3 + 2];
        float ca, sa, cb, sb, cg, sg;
        sincosf(0.5f * a, &sa, &ca);
        sincosf(0.5f * b, &sb, &cb);
        sincosf(0.5f * g, &sg, &cg);
        C2 M00{cb * ca,  sb * sa};
        C2 M01{-sb * ca, -cb * sa};
        C2 M10{sb * ca,  -cb * sa};
        C2 M11{cb * ca,  -sb * sa};
        C2 em{cg, -sg}, ep{cg, sg};
        C2 U00 = cmul(em, M00), U01 = cmul(em, M01);
        C2 U10 = cmul(ep, M10), U11 = cmul(ep, M11);
        float* o = &sU[tid * 8];
        o[0] = U00.re; o[1] = U00.im; o[2] = U01.re; o[3] = U01.im;
        o[4] = U10.re; o[5] = U10.im; o[6] = U11.re; o[7] = U11.im;
    }
    __syncthreads();

    const int r = tid >> 4;       // row 0..15
    const int c = tid & 15;       // col 0..15

    // ---- 2) layer matrices: L_l[r][c] = prod_q U_q[r_q][perm(c)_q] ----
    {
        int b0 = (c >> 3) & 1, b1 = (c >> 2) & 1, b2 = (c >> 1) & 1, b3 = c & 1;
        b1 ^= b0; b2 ^= b1; b3 ^= b2; b0 ^= b3;
        const int r0 = (r >> 3) & 1, r1 = (r >> 2) & 1, r2 = (r >> 1) & 1, r3 = r & 1;
        const int o0 = (r0 * 2 + b0) * 2;
        const int o1 = (r1 * 2 + b1) * 2;
        const int o2 = (r2 * 2 + b2) * 2;
        const int o3 = (r3 * 2 + b3) * 2;
#pragma unroll
        for (int l = 0; l < NL; ++l) {
            const float* g = &sU[l * 32];
            C2 a{g[o0], g[o0 + 1]};
            a = cmul(a, C2{g[8  + o1], g[8  + o1 + 1]});
            a = cmul(a, C2{g[16 + o2], g[16 + o2 + 1]});
            a = cmul(a, C2{g[24 + o3], g[24 + o3 + 1]});
            sL[l][r * LP + c] = make_float2(a.re, a.im);
        }
    }
    __syncthreads();

    // ---- 3a) A = L1*L0, B = L3*L2, C = L5*L4 ----
#pragma unroll
    for (int s = 0; s < 3; ++s) {
        float re = 0.f, im = 0.f;
#pragma unroll
        for (int k = 0; k < 16; ++k) {
            const float2 xk = sL[2 * s + 1][r * LP + k];
            const float2 yk = sL[2 * s][k * LP + c];
            re = __builtin_fmaf(xk.x, yk.x, re); re = __builtin_fmaf(-xk.y, yk.y, re);
            im = __builtin_fmaf(xk.x, yk.y, im); im = __builtin_fmaf( xk.y, yk.x, im);
        }
        sP[s][r * LP + c] = make_float2(re, im);
    }
    __syncthreads();

    // ---- 3b) D = B*A ----
    {
        float re = 0.f, im = 0.f;
#pragma unroll
        for (int k = 0; k < 16; ++k) {
            const float2 xk = sP[1][r * LP + k];
            const float2 yk = sP[0][k * LP + c];
            re = __builtin_fmaf(xk.x, yk.x, re); re = __builtin_fmaf(-xk.y, yk.y, re);
            im = __builtin_fmaf(xk.x, yk.y, im); im = __builtin_fmaf( xk.y, yk.x, im);
        }
        sDm[r * LP + c] = make_float2(re, im);
    }
    __syncthreads();

    // ---- 3c) V = C*D, fold (-i)^popcount(c), pack for matvec ----
    {
        float re = 0.f, im = 0.f;
#pragma unroll
        for (int k = 0; k < 16; ++k) {
            const float2 xk = sP[2][r * LP + k];
            const float2 yk = sDm[k * LP + c];
            re = __builtin_fmaf(xk.x, yk.x, re); re = __builtin_fmaf(-xk.y, yk.y, re);
            im = __builtin_fmaf(xk.x, yk.y, im); im = __builtin_fmaf( xk.y, yk.x, im);
        }
        const int p4 = __popc(c) & 3;   // *(-i)^popcount: 0:(a,b) 1:(b,-a) 2:(-a,-b) 3:(-b,a)
        float wr, wi;
        if      (p4 == 0) { wr = re;  wi = im;  }
        else if (p4 == 1) { wr = im;  wi = -re; }
        else if (p4 == 2) { wr = -re; wi = -im; }
        else              { wr = -im; wi = re;  }
        float* sVf = reinterpret_cast<float*>(sV4);
        reinterpret_cast<float2*>(&sVf[r * 32 + 2 * c])[0] = make_float2(wr, wi);
    }
    __syncthreads();

    // ---- 4) matvec + expectation values (8 elements per thread) ----
    float ev[EPT][4];
#pragma unroll
    for (int e = 0; e < EPT; ++e)
#pragma unroll
        for (int q = 0; q < 4; ++q) ev[e][q] = 0.f;

#pragma unroll
    for (int rr = 0; rr < 16; ++rr) {
        float4 row[8];
#pragma unroll
        for (int k = 0; k < 8; ++k) row[k] = sV4[rr * 8 + k];   // broadcast reads
#pragma unroll
        for (int e = 0; e < EPT; ++e) {
            float re = 0.f, im = 0.f;
#pragma unroll
            for (int k = 0; k < 8; ++k) {
                re = __builtin_fmaf(m[e][2 * k],     row[k].x, re);
                im = __builtin_fmaf(m[e][2 * k],     row[k].y, im);
                re = __builtin_fmaf(m[e][2 * k + 1], row[k].z, re);
                im = __builtin_fmaf(m[e][2 * k + 1], row[k].w, im);
            }
            const float p = __builtin_fmaf(re, re, im * im);
            if (rr & 8) ev[e][0] -= p; else ev[e][0] += p;
            if (rr & 4) ev[e][1] -= p; else ev[e][1] += p;
            if (rr & 2) ev[e][2] -= p; else ev[e][2] += p;
            if (rr & 1) ev[e][3] -= p; else ev[e][3] += p;
        }
    }

#pragma unroll
    for (int e = 0; e < EPT; ++e) {
        out[base + e * 256] = make_float4(ev[e][0], ev[e][1], ev[e][2], ev[e][3]);
    }
}

extern "C" void kernel_launch(void* const* d_in, const int* in_sizes, int n_in,
                              void* d_out, int out_size, void* d_ws, size_t ws_size,
                              hipStream_t stream) {
    const float4* x = (const float4*)d_in[0];   // [B,4] f32
    const float*  w = (const float*)d_in[1];    // [6,4,3] f32
    float4* out = (float4*)d_out;               // [B,4] f32

    qone8_kernel<<<NBLK, 256, 0, stream>>>(x, w, out);
}

// Round 13
// 23.774 us; speedup vs baseline: 2.7060x; 2.7060x over previous
//
#include <hip/hip_runtime.h>
#include <math.h>

#define NQ 4
#define NL 6
#define BATCH 524288
#define EPT 2
#define LP 17   // padded row stride (float2) for V-build matmuls
#define NBLK (BATCH / (256 * EPT))   // 1024 blocks -> 4 blocks/CU at <=128 VGPR

struct C2 { float re, im; };

__device__ __forceinline__ C2 cmul(C2 a, C2 b) {
    return C2{ __builtin_fmaf(a.re, b.re, -a.im * b.im),
               __builtin_fmaf(a.re, b.im,  a.im * b.re) };
}

// ---------------------------------------------------------------------------
// ONE kernel (single graph node). R9 structure, occupancy-tuned:
// EPT=2 -> 1024 blocks; __launch_bounds__(256,4) caps VGPR at 128 so
// 4 blocks/CU are co-resident (4 waves/SIMD) -- R9 ran at 2 waves/SIMD and
// was ~3x latency-exposed (VALU floor ~5.5us vs 19.2 measured, VALUBusy ~17%).
//   0) all threads: x loads + sincos + m[2][16] (regs)
//   1) tid<24: fused U = RZ*RY*RX gates -> sU                    [barrier]
//   2) layer matrices L_l[r][c] = prod_q U_q[r_q][perm(c)_q]     [barrier]
//   3) tree matmul A=L1*L0,B=L3*L2,C=L5*L4 / D=B*A / V=C*D,
//      fold (-i)^popcount(c) -> sV4                              [barriers]
//   4) matvec: per row 8 broadcast b128 reads amortized over 2 elements,
//      ev_q = sum_r z_q(r)|psi_r|^2, coalesced float4 stores.
// R12 lesson: no big per-thread arrays (m[8][16] spilled -> 76MB scratch).
// ---------------------------------------------------------------------------
__global__ __launch_bounds__(256, 4) void qone2_kernel(const float4* __restrict__ x,
                                                       const float* __restrict__ w,
                                                       float4* __restrict__ out) {
    __shared__ float  sU[NL * NQ * 8];
    __shared__ float2 sL[NL][16 * LP];
    __shared__ float2 sP[3][16 * LP];
    __shared__ float2 sDm[16 * LP];
    __shared__ float4 sV4[128];              // V rows for matvec

    const int tid = threadIdx.x;
    const int base = blockIdx.x * (256 * EPT) + tid;

    // ---- 0) per-element Kronecker vectors (2 elements, regs) ----
    float m[EPT][16];
#pragma unroll
    for (int e = 0; e < EPT; ++e) {
        const float4 xv = x[base + e * 256];
        float c0, s0, c1, s1, c2, s2, c3, s3;
        __sincosf(0.5f * xv.x, &s0, &c0);
        __sincosf(0.5f * xv.y, &s1, &c1);
        __sincosf(0.5f * xv.z, &s2, &c2);
        __sincosf(0.5f * xv.w, &s3, &c3);
        float ab[4];
        ab[0] = c0 * c1; ab[1] = c0 * s1; ab[2] = s0 * c1; ab[3] = s0 * s1;
        float abc[8];
#pragma unroll
        for (int k = 0; k < 4; ++k) { abc[2 * k] = ab[k] * c2; abc[2 * k + 1] = ab[k] * s2; }
#pragma unroll
        for (int k = 0; k < 8; ++k) { m[e][2 * k] = abc[k] * c3; m[e][2 * k + 1] = abc[k] * s3; }
    }

    // ---- 1) fused gate matrices (24 threads) ----
    if (tid < NL * NQ) {
        const float a = w[tid * 3 + 0];
        const float b = w[tid * 3 + 1];
        const float g = w[tid * 3 + 2];
        float ca, sa, cb, sb, cg, sg;
        sincosf(0.5f * a, &sa, &ca);
        sincosf(0.5f * b, &sb, &cb);
        sincosf(0.5f * g, &sg, &cg);
        C2 M00{cb * ca,  sb * sa};
        C2 M01{-sb * ca, -cb * sa};
        C2 M10{sb * ca,  -cb * sa};
        C2 M11{cb * ca,  -sb * sa};
        C2 em{cg, -sg}, ep{cg, sg};
        C2 U00 = cmul(em, M00), U01 = cmul(em, M01);
        C2 U10 = cmul(ep, M10), U11 = cmul(ep, M11);
        float* o = &sU[tid * 8];
        o[0] = U00.re; o[1] = U00.im; o[2] = U01.re; o[3] = U01.im;
        o[4] = U10.re; o[5] = U10.im; o[6] = U11.re; o[7] = U11.im;
    }
    __syncthreads();

    const int r = tid >> 4;       // row 0..15
    const int c = tid & 15;       // col 0..15

    // ---- 2) layer matrices: L_l[r][c] = prod_q U_q[r_q][perm(c)_q] ----
    {
        int b0 = (c >> 3) & 1, b1 = (c >> 2) & 1, b2 = (c >> 1) & 1, b3 = c & 1;
        b1 ^= b0; b2 ^= b1; b3 ^= b2; b0 ^= b3;
        const int r0 = (r >> 3) & 1, r1 = (r >> 2) & 1, r2 = (r >> 1) & 1, r3 = r & 1;
        const int o0 = (r0 * 2 + b0) * 2;
        const int o1 = (r1 * 2 + b1) * 2;
        const int o2 = (r2 * 2 + b2) * 2;
        const int o3 = (r3 * 2 + b3) * 2;
#pragma unroll
        for (int l = 0; l < NL; ++l) {
            const float* g = &sU[l * 32];
            C2 a{g[o0], g[o0 + 1]};
            a = cmul(a, C2{g[8  + o1], g[8  + o1 + 1]});
            a = cmul(a, C2{g[16 + o2], g[16 + o2 + 1]});
            a = cmul(a, C2{g[24 + o3], g[24 + o3 + 1]});
            sL[l][r * LP + c] = make_float2(a.re, a.im);
        }
    }
    __syncthreads();

    // ---- 3a) A = L1*L0, B = L3*L2, C = L5*L4 ----
#pragma unroll
    for (int s = 0; s < 3; ++s) {
        float re = 0.f, im = 0.f;
#pragma unroll
        for (int k = 0; k < 16; ++k) {
            const float2 xk = sL[2 * s + 1][r * LP + k];
            const float2 yk = sL[2 * s][k * LP + c];
            re = __builtin_fmaf(xk.x, yk.x, re); re = __builtin_fmaf(-xk.y, yk.y, re);
            im = __builtin_fmaf(xk.x, yk.y, im); im = __builtin_fmaf( xk.y, yk.x, im);
        }
        sP[s][r * LP + c] = make_float2(re, im);
    }
    __syncthreads();

    // ---- 3b) D = B*A ----
    {
        float re = 0.f, im = 0.f;
#pragma unroll
        for (int k = 0; k < 16; ++k) {
            const float2 xk = sP[1][r * LP + k];
            const float2 yk = sP[0][k * LP + c];
            re = __builtin_fmaf(xk.x, yk.x, re); re = __builtin_fmaf(-xk.y, yk.y, re);
            im = __builtin_fmaf(xk.x, yk.y, im); im = __builtin_fmaf( xk.y, yk.x, im);
        }
        sDm[r * LP + c] = make_float2(re, im);
    }
    __syncthreads();

    // ---- 3c) V = C*D, fold (-i)^popcount(c), pack for matvec ----
    {
        float re = 0.f, im = 0.f;
#pragma unroll
        for (int k = 0; k < 16; ++k) {
            const float2 xk = sP[2][r * LP + k];
            const float2 yk = sDm[k * LP + c];
            re = __builtin_fmaf(xk.x, yk.x, re); re = __builtin_fmaf(-xk.y, yk.y, re);
            im = __builtin_fmaf(xk.x, yk.y, im); im = __builtin_fmaf( xk.y, yk.x, im);
        }
        const int p4 = __popc(c) & 3;   // *(-i)^popcount: 0:(a,b) 1:(b,-a) 2:(-a,-b) 3:(-b,a)
        float wr, wi;
        if      (p4 == 0) { wr = re;  wi = im;  }
        else if (p4 == 1) { wr = im;  wi = -re; }
        else if (p4 == 2) { wr = -re; wi = -im; }
        else              { wr = -im; wi = re;  }
        float* sVf = reinterpret_cast<float*>(sV4);
        reinterpret_cast<float2*>(&sVf[r * 32 + 2 * c])[0] = make_float2(wr, wi);
    }
    __syncthreads();

    // ---- 4) matvec + expectation values (2 elements per thread) ----
    float ev[EPT][4];
#pragma unroll
    for (int e = 0; e < EPT; ++e)
#pragma unroll
        for (int q = 0; q < 4; ++q) ev[e][q] = 0.f;

#pragma unroll
    for (int rr = 0; rr < 16; ++rr) {
        float4 row[8];
#pragma unroll
        for (int k = 0; k < 8; ++k) row[k] = sV4[rr * 8 + k];   // broadcast reads
#pragma unroll
        for (int e = 0; e < EPT; ++e) {
            float re = 0.f, im = 0.f;
#pragma unroll
            for (int k = 0; k < 8; ++k) {
                re = __builtin_fmaf(m[e][2 * k],     row[k].x, re);
                im = __builtin_fmaf(m[e][2 * k],     row[k].y, im);
                re = __builtin_fmaf(m[e][2 * k + 1], row[k].z, re);
                im = __builtin_fmaf(m[e][2 * k + 1], row[k].w, im);
            }
            const float p = __builtin_fmaf(re, re, im * im);
            if (rr & 8) ev[e][0] -= p; else ev[e][0] += p;
            if (rr & 4) ev[e][1] -= p; else ev[e][1] += p;
            if (rr & 2) ev[e][2] -= p; else ev[e][2] += p;
            if (rr & 1) ev[e][3] -= p; else ev[e][3] += p;
        }
    }

#pragma unroll
    for (int e = 0; e < EPT; ++e) {
        out[base + e * 256] = make_float4(ev[e][0], ev[e][1], ev[e][2], ev[e][3]);
    }
}

extern "C" void kernel_launch(void* const* d_in, const int* in_sizes, int n_in,
                              void* d_out, int out_size, void* d_ws, size_t ws_size,
                              hipStream_t stream) {
    const float4* x = (const float4*)d_in[0];   // [B,4] f32
    const float*  w = (const float*)d_in[1];    // [6,4,3] f32
    float4* out = (float4*)d_out;               // [B,4] f32

    qone2_kernel<<<NBLK, 256, 0, stream>>>(x, w, out);
}

// Round 14
// 21.564 us; speedup vs baseline: 2.9834x; 1.1025x over previous
//
#include <hip/hip_runtime.h>
#include <math.h>

#define NQ 4
#define NL 6
#define BATCH 524288
#define LP 17                    // padded row stride (float2) for V-build matmuls
#define NTILE (BATCH / 16)       // 32768 tiles of 16 elements
#define NBLK 512
#define WPB 4                    // waves per block (256 threads)
#define NWAVE (NBLK * WPB)       // 2048 waves -> 16 tiles/wave, no tail

typedef __attribute__((ext_vector_type(8))) short bf16x8;  // 8 bf16 = 4 VGPRs
typedef __attribute__((ext_vector_type(4))) float f32x4;

struct C2 { float re, im; };

__device__ __forceinline__ C2 cmul(C2 a, C2 b) {
    return C2{ __builtin_fmaf(a.re, b.re, -a.im * b.im),
               __builtin_fmaf(a.re, b.im,  a.im * b.re) };
}

// float -> bf16 (round-nearest-even) and back
__device__ __forceinline__ unsigned short f2bf(float f) {
    unsigned u = __float_as_uint(f);
    u = u + 0x7FFFu + ((u >> 16) & 1u);
    return (unsigned short)(u >> 16);
}
__device__ __forceinline__ float bf2f(unsigned short b) {
    return __uint_as_float(((unsigned)b) << 16);
}

// ---------------------------------------------------------------------------
// ONE kernel. R9's verified tree V-build + MFMA hot loop (zero LDS in loop).
// R9 was LDS-pipe bound (~9us/CU of ds_read traffic, VALUBusy 17%): V went
// through the one-per-CU LDS pipe 128x b128 per thread. Here V lives in each
// lane's A-fragment registers; psi = V*m done by mfma_f32_16x16x32_bf16 with
// bf16 hi/lo split packed into the K=32 halves:
//   MFMA1: A=[Vhi|Vlo], B=[mhi|mhi]  -> (Vhi+Vlo)*mhi
//   MFMA2: A=[Vhi| 0 ], B=[mlo|mlo]  -> Vhi*mlo      (err ~ Vlo*mlo ~ 2^-18)
// D layout (HW-verified): col=lane&15 = element, row=(lane>>4)*4+reg = psi row.
// Epilogue: p=re^2+im^2; q0/q1 signs depend only on lane-group, q2/q3 only on
// reg index -> 2x shfl_xor(16,32) butterfly; lanes 0..15 store float4.
// ---------------------------------------------------------------------------
__global__ __launch_bounds__(256, 4) void qmfma_kernel(const float4* __restrict__ x,
                                                       const float* __restrict__ w,
                                                       float4* __restrict__ out) {
    __shared__ float  sU[NL * NQ * 8];
    __shared__ float2 sL[NL][16 * LP];
    __shared__ float2 sP[3][16 * LP];
    __shared__ float2 sDm[16 * LP];
    __shared__ float  sVf[16 * 32];          // V[r][c] -> (re,im) at r*32+2c

    const int tid = threadIdx.x;

    // ---- V-build (verbatim R9/R13, verified 5 rounds) ----
    if (tid < NL * NQ) {
        const float a = w[tid * 3 + 0];
        const float b = w[tid * 3 + 1];
        const float g = w[tid * 3 + 2];
        float ca, sa, cb, sb, cg, sg;
        sincosf(0.5f * a, &sa, &ca);
        sincosf(0.5f * b, &sb, &cb);
        sincosf(0.5f * g, &sg, &cg);
        C2 M00{cb * ca,  sb * sa};
        C2 M01{-sb * ca, -cb * sa};
        C2 M10{sb * ca,  -cb * sa};
        C2 M11{cb * ca,  -sb * sa};
        C2 em{cg, -sg}, ep{cg, sg};
        C2 U00 = cmul(em, M00), U01 = cmul(em, M01);
        C2 U10 = cmul(ep, M10), U11 = cmul(ep, M11);
        float* o = &sU[tid * 8];
        o[0] = U00.re; o[1] = U00.im; o[2] = U01.re; o[3] = U01.im;
        o[4] = U10.re; o[5] = U10.im; o[6] = U11.re; o[7] = U11.im;
    }
    __syncthreads();

    {
        const int r = tid >> 4, c = tid & 15;
        int b0 = (c >> 3) & 1, b1 = (c >> 2) & 1, b2 = (c >> 1) & 1, b3 = c & 1;
        b1 ^= b0; b2 ^= b1; b3 ^= b2; b0 ^= b3;
        const int r0 = (r >> 3) & 1, r1 = (r >> 2) & 1, r2 = (r >> 1) & 1, r3 = r & 1;
        const int o0 = (r0 * 2 + b0) * 2;
        const int o1 = (r1 * 2 + b1) * 2;
        const int o2 = (r2 * 2 + b2) * 2;
        const int o3 = (r3 * 2 + b3) * 2;
#pragma unroll
        for (int l = 0; l < NL; ++l) {
            const float* g = &sU[l * 32];
            C2 a{g[o0], g[o0 + 1]};
            a = cmul(a, C2{g[8  + o1], g[8  + o1 + 1]});
            a = cmul(a, C2{g[16 + o2], g[16 + o2 + 1]});
            a = cmul(a, C2{g[24 + o3], g[24 + o3 + 1]});
            sL[l][r * LP + c] = make_float2(a.re, a.im);
        }
    }
    __syncthreads();

    {
        const int r = tid >> 4, c = tid & 15;
#pragma unroll
        for (int s = 0; s < 3; ++s) {
            float re = 0.f, im = 0.f;
#pragma unroll
            for (int k = 0; k < 16; ++k) {
                const float2 xk = sL[2 * s + 1][r * LP + k];
                const float2 yk = sL[2 * s][k * LP + c];
                re = __builtin_fmaf(xk.x, yk.x, re); re = __builtin_fmaf(-xk.y, yk.y, re);
                im = __builtin_fmaf(xk.x, yk.y, im); im = __builtin_fmaf( xk.y, yk.x, im);
            }
            sP[s][r * LP + c] = make_float2(re, im);
        }
    }
    __syncthreads();
    {
        const int r = tid >> 4, c = tid & 15;
        float re = 0.f, im = 0.f;
#pragma unroll
        for (int k = 0; k < 16; ++k) {
            const float2 xk = sP[1][r * LP + k];
            const float2 yk = sP[0][k * LP + c];
            re = __builtin_fmaf(xk.x, yk.x, re); re = __builtin_fmaf(-xk.y, yk.y, re);
            im = __builtin_fmaf(xk.x, yk.y, im); im = __builtin_fmaf( xk.y, yk.x, im);
        }
        sDm[r * LP + c] = make_float2(re, im);
    }
    __syncthreads();
    {
        const int r = tid >> 4, c = tid & 15;
        float re = 0.f, im = 0.f;
#pragma unroll
        for (int k = 0; k < 16; ++k) {
            const float2 xk = sP[2][r * LP + k];
            const float2 yk = sDm[k * LP + c];
            re = __builtin_fmaf(xk.x, yk.x, re); re = __builtin_fmaf(-xk.y, yk.y, re);
            im = __builtin_fmaf(xk.x, yk.y, im); im = __builtin_fmaf( xk.y, yk.x, im);
        }
        const int p4 = __popc(c) & 3;   // fold (-i)^popcount(c)
        float wr, wi;
        if      (p4 == 0) { wr = re;  wi = im;  }
        else if (p4 == 1) { wr = im;  wi = -re; }
        else if (p4 == 2) { wr = -re; wi = -im; }
        else              { wr = -im; wi = re;  }
        reinterpret_cast<float2*>(&sVf[r * 32 + 2 * c])[0] = make_float2(wr, wi);
    }
    __syncthreads();

    // ---- A fragments: V in registers (once per wave) ----
    // A[row=l&15][k=(l>>4)*8+j]; k<16 half: Vhi; k>=16 half: Vlo (A1) / 0 (A2)
    const int l  = tid & 63;
    const int rA = l & 15;
    const int g  = l >> 4;       // lane group 0..3
    const int gh = g & 1;
    bf16x8 A1re, A1im, A2re, A2im;
#pragma unroll
    for (int j = 0; j < 8; ++j) {
        const int c = 8 * gh + j;
        const float vr = sVf[rA * 32 + 2 * c];
        const float vi = sVf[rA * 32 + 2 * c + 1];
        const unsigned short hr = f2bf(vr), hi_ = f2bf(vi);
        if (g < 2) {
            A1re[j] = (short)hr;  A1im[j] = (short)hi_;
            A2re[j] = (short)hr;  A2im[j] = (short)hi_;
        } else {
            A1re[j] = (short)f2bf(vr - bf2f(hr));
            A1im[j] = (short)f2bf(vi - bf2f(hi_));
            A2re[j] = 0;          A2im[j] = 0;
        }
    }

    // ---- hot loop: 16 tiles per wave, zero LDS ----
    const int wg = (blockIdx.x << 2) + (tid >> 6);   // global wave id
    const int e  = l & 15;                           // element within tile
    const float sgn0 = (g & 2) ? -1.f : 1.f;         // q0 sign: row&8 = g&2
    const float sgn1 = (g & 1) ? -1.f : 1.f;         // q1 sign: row&4 = g&1

    int t = wg;
    float4 xv = x[t * 16 + e];
    while (t < NTILE) {
        const int tn = t + NWAVE;
        float4 xnext = xv;
        if (tn < NTILE) xnext = x[tn * 16 + e];      // prefetch next tile

        float c0, s0, c1, s1, c2, s2, c3, s3;
        __sincosf(0.5f * xv.x, &s0, &c0);
        __sincosf(0.5f * xv.y, &s1, &c1);
        __sincosf(0.5f * xv.z, &s2, &c2);
        __sincosf(0.5f * xv.w, &s3, &c3);

        // this lane's 8 m-values: k = 8*gh + j, bits (gh, j>>2, (j>>1)&1, j&1)
        const float f0 = gh ? s0 : c0;
        const float t0 = f0 * c1, t1 = f0 * s1;
        const float u0 = t0 * c2, u1 = t0 * s2, u2 = t1 * c2, u3 = t1 * s2;
        float mv[8];
        mv[0] = u0 * c3; mv[1] = u0 * s3; mv[2] = u1 * c3; mv[3] = u1 * s3;
        mv[4] = u2 * c3; mv[5] = u2 * s3; mv[6] = u3 * c3; mv[7] = u3 * s3;

        bf16x8 B1, B2;
#pragma unroll
        for (int j = 0; j < 8; ++j) {
            const unsigned short h = f2bf(mv[j]);
            B1[j] = (short)h;
            B2[j] = (short)f2bf(mv[j] - bf2f(h));
        }

        f32x4 dre = {0.f, 0.f, 0.f, 0.f}, dim = {0.f, 0.f, 0.f, 0.f};
        dre = __builtin_amdgcn_mfma_f32_16x16x32_bf16(A1re, B1, dre, 0, 0, 0);
        dre = __builtin_amdgcn_mfma_f32_16x16x32_bf16(A2re, B2, dre, 0, 0, 0);
        dim = __builtin_amdgcn_mfma_f32_16x16x32_bf16(A1im, B1, dim, 0, 0, 0);
        dim = __builtin_amdgcn_mfma_f32_16x16x32_bf16(A2im, B2, dim, 0, 0, 0);

        // epilogue: p = re^2+im^2 for this lane's 4 rows (rows 4g..4g+3)
        const float p0 = __builtin_fmaf(dre[0], dre[0], dim[0] * dim[0]);
        const float p1 = __builtin_fmaf(dre[1], dre[1], dim[1] * dim[1]);
        const float p2 = __builtin_fmaf(dre[2], dre[2], dim[2] * dim[2]);
        const float p3 = __builtin_fmaf(dre[3], dre[3], dim[3] * dim[3]);
        const float a_ = p0 + p1, b_ = p2 + p3;
        float v0 = sgn0 * (a_ + b_);                 // q0
        float v1 = sgn1 * (a_ + b_);                 // q1
        float v2 = a_ - b_;                          // q2: rows' bit1 = reg>>1
        float v3 = (p0 - p1) + (p2 - p3);            // q3: rows' bit0 = reg&1

        v0 += __shfl_xor(v0, 16); v1 += __shfl_xor(v1, 16);
        v2 += __shfl_xor(v2, 16); v3 += __shfl_xor(v3, 16);
        v0 += __shfl_xor(v0, 32); v1 += __shfl_xor(v1, 32);
        v2 += __shfl_xor(v2, 32); v3 += __shfl_xor(v3, 32);

        if (l < 16) out[t * 16 + e] = make_float4(v0, v1, v2, v3);

        t = tn;
        xv = xnext;
    }
}

extern "C" void kernel_launch(void* const* d_in, const int* in_sizes, int n_in,
                              void* d_out, int out_size, void* d_ws, size_t ws_size,
                              hipStream_t stream) {
    const float4* x = (const float4*)d_in[0];   // [B,4] f32
    const float*  w = (const float*)d_in[1];    // [6,4,3] f32
    float4* out = (float4*)d_out;               // [B,4] f32

    qmfma_kernel<<<NBLK, 256, 0, stream>>>(x, w, out);
}